// Round 10
// baseline (298.209 us; speedup 1.0000x reference)
//
#include <hip/hip_runtime.h>
#include <stdint.h>

#define BB 4
#define CCH 64
#define NN 9216      // 96*96
#define NTILES 144   // NN/64  (qkv: 64-wide n tiles)
#define FTILES 36    // NN/256 (flash: 256 Q-rows per block, 64 per wave)
#define NCHUNK 5     // split-K chunks, uneven (29,29,29,29,28 iters of 64 keys)

typedef unsigned short u16;
typedef __attribute__((ext_vector_type(8))) short bhalf8;   // 8 bf16 lanes of an MFMA operand
typedef __attribute__((ext_vector_type(4))) float f32x4;
typedef __attribute__((ext_vector_type(4))) u16 u16x4;
typedef __attribute__((ext_vector_type(8))) u16 u16x8;
typedef __attribute__((ext_vector_type(2))) unsigned int u32x2;

#define MFMA16(a, b, c) __builtin_amdgcn_mfma_f32_16x16x32_bf16((a), (b), (c), 0, 0, 0)

static __device__ __forceinline__ u16 f2bf(float f) {
  union { float f; unsigned u; } v; v.f = f;
  return (u16)((v.u + 0x7fffu + ((v.u >> 16) & 1u)) >> 16);  // RNE
}
static __device__ __forceinline__ float bf2f(u16 h) {
  union { unsigned u; float f; } v; v.u = ((unsigned)h) << 16; return v.f;
}
// pack two f32 -> (bf16(hi)<<16)|bf16(lo), round-half-up, 3 VALU ops total
static __device__ __forceinline__ unsigned pk2(float lo, float hi) {
  unsigned a = __float_as_uint(hi) + 0x8000u;
  unsigned b = __float_as_uint(lo) + 0x8000u;
  return __builtin_amdgcn_perm(a, b, 0x07060302u);  // bytes {a3,a2,b3,b2}
}
// async global->LDS, 16B per lane; lds dest = wave-uniform base + lane*16
static __device__ __forceinline__ void glds16(const void* g, void* l) {
  __builtin_amdgcn_global_load_lds(
      (const __attribute__((address_space(1))) unsigned int*)g,
      (__attribute__((address_space(3))) unsigned int*)l, 16, 0, 0);
}

// ---------------------------------------------------------------------------
// prep: blocks [0,256): per-(b,c) mean/rstd over 9216 spatial elems (float4).
//       blocks [256,320): convert wq,wk,wv,wo (4*4096 f32) to bf16.
// ---------------------------------------------------------------------------
extern "C" __global__ __launch_bounds__(256) void prep_kernel(
    const float* __restrict__ x,
    const float* __restrict__ wq, const float* __restrict__ wk,
    const float* __restrict__ wv, const float* __restrict__ wo,
    float* __restrict__ mean, float* __restrict__ rstd, u16* __restrict__ wbf) {
  if (blockIdx.x >= 256) {
    int i = (blockIdx.x - 256) * 256 + threadIdx.x;  // 0..16383
    const float* src = (i < 4096) ? wq : (i < 8192) ? wk : (i < 12288) ? wv : wo;
    wbf[i] = f2bf(src[i & 4095]);
    return;
  }
  int idx = blockIdx.x;
  const f32x4* p4 = (const f32x4*)(x + (size_t)idx * NN);
  float s = 0.f, ss = 0.f;
  for (int i = threadIdx.x; i < NN / 4; i += 256) {
    f32x4 v = p4[i];
#pragma unroll
    for (int j = 0; j < 4; j++) { s += v[j]; ss += v[j] * v[j]; }
  }
#pragma unroll
  for (int o = 32; o > 0; o >>= 1) { s += __shfl_xor(s, o, 64); ss += __shfl_xor(ss, o, 64); }
  __shared__ float ls[4], lss[4];
  int w = threadIdx.x >> 6;
  if ((threadIdx.x & 63) == 0) { ls[w] = s; lss[w] = ss; }
  __syncthreads();
  if (threadIdx.x == 0) {
    s = ls[0] + ls[1] + ls[2] + ls[3];
    ss = lss[0] + lss[1] + lss[2] + lss[3];
    float m = s * (1.f / NN);
    float var = ss * (1.f / NN) - m * m;
    mean[idx] = m;
    rstd[idx] = rsqrtf(var + 1e-5f);
  }
}

// ---------------------------------------------------------------------------
// qkv: fused instance-norm + 1x1 convs via MFMA, LDS-transpose epilogues for
// fully-coalesced stores (R9 win).
// Qt,Kt = [B][N][64] bf16 (Q pre-scaled by 0.125*log2e), Vt = [B][64][N] bf16.
// ---------------------------------------------------------------------------
extern "C" __global__ __launch_bounds__(256, 4) void qkv_kernel(
    const float* __restrict__ x,
    const float* __restrict__ mean, const float* __restrict__ rstd,
    const u16* __restrict__ wqb, const u16* __restrict__ wkb, const u16* __restrict__ wvb,
    const float* __restrict__ bq, const float* __restrict__ bk,
    u16* __restrict__ Qt, u16* __restrict__ Kt, u16* __restrict__ Vt) {
  __shared__ u16 smem[64 * 72];  // staging hbuf (stride 72), then transpose tile (stride 68)
  int b = blockIdx.x / NTILES, tile = blockIdx.x % NTILES;
  int n0 = tile * 64;
  int t = threadIdx.x;
  int w = t >> 6, lane = t & 63, q = lane >> 4, ln = lane & 15;
  const float QSCALE = 0.125f * 1.44269504088896340736f;  // C^-0.5 * log2(e)
  const float* mb = mean + b * 64;
  const float* rb_ = rstd + b * 64;
  int nloc = lane;
#pragma unroll
  for (int rep = 0; rep < 4; rep++) {
    int c0 = 16 * w + 4 * rep;  // wave-uniform
    float h0 = (x[(size_t)(b * 64 + c0 + 0) * NN + n0 + nloc] - mb[c0 + 0]) * rb_[c0 + 0];
    float h1 = (x[(size_t)(b * 64 + c0 + 1) * NN + n0 + nloc] - mb[c0 + 1]) * rb_[c0 + 1];
    float h2 = (x[(size_t)(b * 64 + c0 + 2) * NN + n0 + nloc] - mb[c0 + 2]) * rb_[c0 + 2];
    float h3 = (x[(size_t)(b * 64 + c0 + 3) * NN + n0 + nloc] - mb[c0 + 3]) * rb_[c0 + 3];
    u32x2 hp;
    hp[0] = pk2(h0, h1);
    hp[1] = pk2(h2, h3);
    *(u32x2*)&smem[nloc * 72 + c0] = hp;
  }
  __syncthreads();
  int hrow = (16 * w + ln) * 72;
  bhalf8 hb0 = *(const bhalf8*)&smem[hrow + q * 8];
  bhalf8 hb1 = *(const bhalf8*)&smem[hrow + 32 + q * 8];
  __syncthreads();  // all waves have h-frags in registers; smem is now reusable

  int row_st = t >> 3, ch_st = (t & 7) * 8;  // coalesced-store pass indexing
  // ---- Q (transposed orientation: quad = 4 consecutive channels) ----
#pragma unroll
  for (int ct = 0; ct < 4; ct++) {
    int wrow = (16 * ct + ln) * 64;
    bhalf8 a0 = *(const bhalf8*)&wqb[wrow + q * 8];
    bhalf8 a1 = *(const bhalf8*)&wqb[wrow + 32 + q * 8];
    f32x4 d = {0.f, 0.f, 0.f, 0.f};
    d = MFMA16(a0, hb0, d);
    d = MFMA16(a1, hb1, d);
    f32x4 b4 = *(const f32x4*)&bq[16 * ct + 4 * q];
    u32x2 pk;
    pk[0] = pk2((d[0] + b4[0]) * QSCALE, (d[1] + b4[1]) * QSCALE);
    pk[1] = pk2((d[2] + b4[2]) * QSCALE, (d[3] + b4[3]) * QSCALE);
    *(u32x2*)&smem[(16 * w + ln) * 68 + 16 * ct + 4 * q] = pk;  // [n][c]
  }
  __syncthreads();
#pragma unroll
  for (int pass = 0; pass < 2; pass++) {
    int n = 32 * pass + row_st;
    *(u16x8*)&Qt[(size_t)(b * NN + n0 + n) * 64 + ch_st] = *(const u16x8*)&smem[n * 68 + ch_st];
  }
  __syncthreads();
  // ---- K ----
#pragma unroll
  for (int ct = 0; ct < 4; ct++) {
    int wrow = (16 * ct + ln) * 64;
    bhalf8 a0 = *(const bhalf8*)&wkb[wrow + q * 8];
    bhalf8 a1 = *(const bhalf8*)&wkb[wrow + 32 + q * 8];
    f32x4 d = {0.f, 0.f, 0.f, 0.f};
    d = MFMA16(a0, hb0, d);
    d = MFMA16(a1, hb1, d);
    f32x4 b4 = *(const f32x4*)&bk[16 * ct + 4 * q];
    u32x2 pk;
    pk[0] = pk2(d[0] + b4[0], d[1] + b4[1]);
    pk[1] = pk2(d[2] + b4[2], d[3] + b4[3]);
    *(u32x2*)&smem[(16 * w + ln) * 68 + 16 * ct + 4 * q] = pk;  // [n][c]
  }
  __syncthreads();
#pragma unroll
  for (int pass = 0; pass < 2; pass++) {
    int n = 32 * pass + row_st;
    *(u16x8*)&Kt[(size_t)(b * NN + n0 + n) * 64 + ch_st] = *(const u16x8*)&smem[n * 68 + ch_st];
  }
  __syncthreads();
  // ---- V (normal orientation: quad = 4 consecutive n; bv folded into merge) ----
#pragma unroll
  for (int ct = 0; ct < 4; ct++) {
    int wrow = (16 * ct + ln) * 64;
    bhalf8 b0 = *(const bhalf8*)&wvb[wrow + q * 8];
    bhalf8 b1 = *(const bhalf8*)&wvb[wrow + 32 + q * 8];
    f32x4 d = {0.f, 0.f, 0.f, 0.f};
    d = MFMA16(hb0, b0, d);
    d = MFMA16(hb1, b1, d);
    u32x2 pk;
    pk[0] = pk2(d[0], d[1]);
    pk[1] = pk2(d[2], d[3]);
    *(u32x2*)&smem[(16 * ct + ln) * 68 + 16 * w + 4 * q] = pk;  // [c][n]
  }
  __syncthreads();
#pragma unroll
  for (int pass = 0; pass < 2; pass++) {
    int c = 32 * pass + row_st;
    *(u16x8*)&Vt[(size_t)(b * 64 + c) * NN + n0 + ch_st] = *(const u16x8*)&smem[c * 68 + ch_st];
  }
}

// ---------------------------------------------------------------------------
// flash: split-K attention, max-free softmax, 64 Q-rows per wave (R7 config)
// + FUSED LAST-BLOCK MERGE: after emitting its partial, each block does a
// device-scope release fence + atomicAdd on a per-tile counter; the 5th
// arrival merges all partials, applies Wo + bias + residual and stores the
// final output, reusing its dead 48KB smem as the f32 transpose tile. The
// merge runs concurrently with other tiles' K-loops on half-idle pipes
// instead of as a serialized out_kernel tail.
// ---------------------------------------------------------------------------
extern "C" __global__ __launch_bounds__(256, 3) void flash_kernel(
    const u16* __restrict__ Qt, const u16* __restrict__ Kt, const u16* __restrict__ Vt,
    u16* __restrict__ Opart, float* __restrict__ Lsum, unsigned* __restrict__ cnt,
    const float* __restrict__ x, const u16* __restrict__ wob,
    const float* __restrict__ bo, const float* __restrict__ bv,
    float* __restrict__ out) {
  __shared__ u16 smem[24576];          // 48KB: kbuf[2][4096] | vbuf[2][4096] | pbuf[4][2048]
  __shared__ int sflag;
  u16* kbufs = smem;                   // [m_local][c], 16B units swizzled by (row&7)
  u16* vbufs = smem + 8192;            // [c][m_local], swizzled
  u16* pbufs = smem + 16384;           // per-wave [n_local(64)][32 keys], 4-unit XOR swizzle
  int blk = blockIdx.x;
  int b = blk / (FTILES * NCHUNK);
  int rem = blk % (FTILES * NCHUNK);
  int tile = rem / NCHUNK, chunk = rem % NCHUNK;
  int it0 = chunk * 28 + (chunk < 4 ? chunk : 4);   // 0,29,58,87,116
  int nit = 28 + (chunk < 4 ? 1 : 0);               // 29,29,29,29,28
  int m_start = it0 * 64;
  int t = threadIdx.x;
  int w = t >> 6, lane = t & 63, q = lane >> 4, ln = lane & 15;
  int n0w = tile * 256 + 64 * w;
  // Q fragments for 4 sets of 16 rows each
  bhalf8 qf0[4], qf1[4];
#pragma unroll
  for (int s = 0; s < 4; s++) {
    const u16* qp = Qt + (size_t)(b * NN + n0w + 16 * s + ln) * 64 + q * 8;
    qf0[s] = *(const bhalf8*)qp;
    qf1[s] = *(const bhalf8*)(qp + 32);
  }
  const short ONE = 0x3F80;            // bf16 1.0
  const bhalf8 ones = {ONE, ONE, ONE, ONE, ONE, ONE, ONE, ONE};
  f32x4 o[4][4];                       // [ct][set]
  f32x4 lacc[4];
#pragma unroll
  for (int ct = 0; ct < 4; ct++) {
    lacc[ct] = (f32x4){0.f, 0.f, 0.f, 0.f};
#pragma unroll
    for (int s = 0; s < 4; s++) o[ct][s] = (f32x4){0.f, 0.f, 0.f, 0.f};
  }
  u16* pw = pbufs + w * 2048;
  // staging: wave w fills LDS rows [16w,16w+16); lane covers (row 16w+(lane>>3), unit lane&7)
  int row_s = 16 * w + (lane >> 3);
  int usw = (lane & 7) ^ (row_s & 7);  // swizzled global 16B-chunk index
  const u16* kgp = Kt + ((size_t)b * NN + m_start + row_s) * 64 + usw * 8;
  const u16* vgp = Vt + (size_t)(b * 64 + row_s) * NN + m_start + usw * 8;
  int sbase = (q ^ (ln & 7)) * 8;      // swizzled chunk offset for K/V fragment reads

  // prologue: DMA tile 0 -> buffer 0
  {
    u16* kl = kbufs + w * 1024;
    u16* vl = vbufs + w * 1024;
    glds16(kgp, kl); glds16(kgp + 512, kl + 512);
    glds16(vgp, vl); glds16(vgp + (size_t)8 * NN, vl + 512);
    kgp += 4096; vgp += 64;
  }

  for (int i = 0; i < nit; i++) {
    __syncthreads();
    if (i + 1 < nit) {                 // prefetch tile i+1 into the other buffer
      u16* kl = kbufs + ((i + 1) & 1) * 4096 + w * 1024;
      u16* vl = vbufs + ((i + 1) & 1) * 4096 + w * 1024;
      glds16(kgp, kl); glds16(kgp + 512, kl + 512);
      glds16(vgp, vl); glds16(vgp + (size_t)8 * NN, vl + 512);
      kgp += 4096; vgp += 64;
    }
    const u16* kb = kbufs + (i & 1) * 4096;
    const u16* vb = vbufs + (i & 1) * 4096;
#pragma unroll
    for (int p = 0; p < 2; p++) {      // two 32-key phases
#pragma unroll
      for (int lm = 0; lm < 2; lm++) { // 16 keys each
        int krow = (16 * (2 * p + lm) + ln) * 64;
        bhalf8 ka0 = *(const bhalf8*)&kb[krow + sbase];
        bhalf8 ka1 = *(const bhalf8*)&kb[krow + (sbase ^ 32)];
        int uw = (((2 * lm + (q >> 1)) ^ ((ln >> 1) & 3)) << 3) + ((q & 1) << 2);
#pragma unroll
        for (int s = 0; s < 4; s++) {
          f32x4 acc = {0.f, 0.f, 0.f, 0.f};
          acc = MFMA16(ka0, qf0[s], acc);
          acc = MFMA16(ka1, qf1[s], acc);
          f32x4 pv;
#pragma unroll
          for (int r = 0; r < 4; r++) pv[r] = __builtin_amdgcn_exp2f(acc[r]);
          u32x2 pk;
          pk[0] = pk2(pv[0], pv[1]);
          pk[1] = pk2(pv[2], pv[3]);
          *(u32x2*)&pw[(16 * s + ln) * 32 + uw] = pk;
        }
      }
      // PV for this 32-key phase: O^T += V^T * P^T ; l via ones-A MFMA
      int ur = ((q ^ ((ln >> 1) & 3)) << 3);
      bhalf8 pf[4];
#pragma unroll
      for (int s = 0; s < 4; s++) pf[s] = *(const bhalf8*)&pw[(16 * s + ln) * 32 + ur];
#pragma unroll
      for (int s = 0; s < 4; s++) lacc[s] = MFMA16(ones, pf[s], lacc[s]);
#pragma unroll
      for (int ct = 0; ct < 4; ct++) {
        bhalf8 va = *(const bhalf8*)&vb[(16 * ct + ln) * 64 + (sbase ^ (32 * p))];
#pragma unroll
        for (int s = 0; s < 4; s++) o[ct][s] = MFMA16(va, pf[s], o[ct][s]);
      }
    }
  }
  // emit partial (unnormalized O in bf16, l per row)
  size_t pbase = (size_t)blk * (256 * 64);
#pragma unroll
  for (int s = 0; s < 4; s++) {
    int row = 64 * w + 16 * s + ln;
#pragma unroll
    for (int ct = 0; ct < 4; ct++) {
      u32x2 pk;
      pk[0] = pk2(o[ct][s][0], o[ct][s][1]);
      pk[1] = pk2(o[ct][s][2], o[ct][s][3]);
      *(u32x2*)&Opart[pbase + (size_t)row * 64 + 16 * ct + 4 * q] = pk;
    }
    if (q == 0) Lsum[(size_t)blk * 256 + row] = lacc[s][0];
  }
  // ---- last-block merge: 5th arrival merges + projects + stores ----
  __syncthreads();                      // LDS no longer needed by K-loop
  if (t == 0) {
    __threadfence();                    // release: partial visible device-wide
    unsigned old = atomicAdd(&cnt[b * FTILES + tile], 1u);
    sflag = (old == NCHUNK - 1);
  }
  __syncthreads();
  if (!sflag) return;
  __threadfence();                      // acquire: see all 5 partials
  float* fbuf = (float*)smem;           // 64*68 f32 = 17.4KB (within 48KB)
  int p0 = (b * FTILES + tile) * NCHUNK;
#pragma unroll
  for (int st = 0; st < 4; st++) {      // four 64-row sub-tiles
    int n0 = tile * 256 + st * 64;
    int prow = st * 64 + 16 * w + ln;   // this lane's merged A-row
    float L = 0.f;
    float acc0[8], acc1[8];
#pragma unroll
    for (int j = 0; j < 8; j++) { acc0[j] = 0.f; acc1[j] = 0.f; }
#pragma unroll
    for (int ch = 0; ch < NCHUNK; ch++) {
      L += Lsum[(size_t)(p0 + ch) * 256 + prow];
      const u16* op = Opart + ((size_t)(p0 + ch) * 256 + prow) * 64;
      u16x8 d0 = *(const u16x8*)(op + 8 * q);
      u16x8 d1 = *(const u16x8*)(op + 32 + 8 * q);
#pragma unroll
      for (int j = 0; j < 8; j++) { acc0[j] += bf2f(d0[j]); acc1[j] += bf2f(d1[j]); }
    }
    float rl = 1.0f / L;
    union { u16x8 us; bhalf8 bh; } A0, A1;
#pragma unroll
    for (int j = 0; j < 8; j++) {
      A0.us[j] = f2bf(acc0[j] * rl + bv[8 * q + j]);
      A1.us[j] = f2bf(acc1[j] * rl + bv[32 + 8 * q + j]);
    }
    bhalf8 a0 = A0.bh, a1 = A1.bh;
#pragma unroll
    for (int ct = 0; ct < 4; ct++) {
      int wrow = (16 * ct + ln) * 64;
      bhalf8 b0 = *(const bhalf8*)&wob[wrow + q * 8];
      bhalf8 b1 = *(const bhalf8*)&wob[wrow + 32 + q * 8];
      f32x4 d = {0.f, 0.f, 0.f, 0.f};
      d = MFMA16(a0, b0, d);
      d = MFMA16(a1, b1, d);
      *(f32x4*)&fbuf[(16 * ct + ln) * 68 + 16 * w + 4 * q] = d;  // [c][n]
    }
    __syncthreads();
    // coalesced epilogue: residual + bias + store, 16B/lane contiguous
#pragma unroll
    for (int pass = 0; pass < 4; pass++) {
      int co = 16 * pass + (t >> 4);
      int chk = t & 15;
      f32x4 v = *(const f32x4*)&fbuf[co * 68 + chk * 4];
      size_t base = (size_t)(b * 64 + co) * NN + n0 + chk * 4;
      f32x4 xv = *(const f32x4*)&x[base];
      float bc = bo[co];
      f32x4 ov;
#pragma unroll
      for (int r = 0; r < 4; r++) ov[r] = xv[r] + bc + v[r];
      *(f32x4*)&out[base] = ov;
    }
    __syncthreads();                    // fbuf reused next sub-tile
  }
}

extern "C" void kernel_launch(void* const* d_in, const int* in_sizes, int n_in,
                              void* d_out, int out_size, void* d_ws, size_t ws_size,
                              hipStream_t stream) {
  (void)in_sizes; (void)n_in; (void)out_size; (void)ws_size;
  const float* x  = (const float*)d_in[0];
  const float* wq = (const float*)d_in[1];
  const float* bq = (const float*)d_in[2];
  const float* wk = (const float*)d_in[3];
  const float* bk = (const float*)d_in[4];
  const float* wv = (const float*)d_in[5];
  const float* bv = (const float*)d_in[6];
  const float* wo = (const float*)d_in[7];
  const float* bo = (const float*)d_in[8];
  float* out = (float*)d_out;
  char* ws = (char*)d_ws;
  // workspace layout (16B aligned), ~39 MB total
  float* mean = (float*)ws;                   // 256 f32
  float* rstd = (float*)(ws + 1024);          // 256 f32
  u16* wbf = (u16*)(ws + 2048);               // 16384 bf16
  u16* Qt = (u16*)(ws + 36864);               // [B][N][64] bf16  4.72MB
  u16* Kt = Qt + (size_t)BB * NN * 64;
  u16* Vt = Kt + (size_t)BB * NN * 64;
  u16* Opart = Vt + (size_t)BB * NN * 64;     // 720 * 256*64 bf16 = 23.6MB
  float* Lsum = (float*)(Opart + (size_t)BB * FTILES * NCHUNK * 256 * 64);  // 720*256 f32
  unsigned* cnt = (unsigned*)(Lsum + (size_t)BB * FTILES * NCHUNK * 256);   // 144 u32
  const u16* wqb = wbf;
  const u16* wkb = wbf + 4096;
  const u16* wvb = wbf + 8192;
  const u16* wob = wbf + 12288;

  hipMemsetAsync(cnt, 0, BB * FTILES * sizeof(unsigned), stream);  // graph-capturable
  prep_kernel<<<320, 256, 0, stream>>>(x, wq, wk, wv, wo, mean, rstd, wbf);
  qkv_kernel<<<BB * NTILES, 256, 0, stream>>>(x, mean, rstd, wqb, wkb, wvb, bq, bk, Qt, Kt, Vt);
  flash_kernel<<<BB * FTILES * NCHUNK, 256, 0, stream>>>(Qt, Kt, Vt, Opart, Lsum, cnt,
                                                         x, wob, bo, bv, out);
}